// Round 1
// baseline (644.093 us; speedup 1.0000x reference)
//
#include <hip/hip_runtime.h>
#include <cmath>
#include <cstdint>
#include <cstddef>

// LIF network. Facts exploited:
//  (1) s==0 forever -> recurrent term dead (recurrent_weights, E/I_weight unused).
//  (2) ff = X @ Wff^T is a GEMM; X is exactly 0/1 -> exact in f16. Weights
//      split f16 hi/lo with x1024 scaling: residual <= 2^-22 relative, below
//      fp32 reorder noise. K = 2048 (hi rows 0..1023, lo rows 1024..2047).
//      Dense MFMA (268 GF total) beats the sparse L2-bound gather
//      (27.5 TB/s measured = 80% L2 ceiling, would floor at ~395 us).
//  (3) ff independent of recurrence -> per T-chunk kernel computes ff(chunk c)
//      via MFMA AND the serial recurrence over chunk c-1 (ping-pong buffers);
//      rec rides under the GEMM for free.
//  GEMM structure: m97 recipe (128x128 tile, BK=32, 4 waves, As/Bs [128][32]
//      f16 in LDS, global_load_lds width 16, 2-barrier K-loop, 16x16x32 MFMA).
//
// ws layout: [ Wt2 (N x 2*NI) f16 | X16 (B*T x NI) f16 |
//              state 2*B*N f32 | ffA | ffB (TC*B*N f32 each) ]

typedef _Float16 half8 __attribute__((ext_vector_type(8)));
typedef float floatx4 __attribute__((ext_vector_type(4)));

#define WSCALE 1024.0f
#define WSCALE_INV (1.0f / 1024.0f)

__device__ __forceinline__ void gload16(const void* g, void* l) {
    __builtin_amdgcn_global_load_lds(
        (const __attribute__((address_space(1))) unsigned int*)g,
        (__attribute__((address_space(3))) unsigned int*)l, 16, 0, 0);
}

// ---- W prep: Wt2[n][k] f16, k<NI: hi(1024*Wff[n][k]); k>=NI: lo residual ----
__global__ __launch_bounds__(256) void k_wprep(const float* __restrict__ Wff,
                                               _Float16* __restrict__ Wt2,
                                               int N, int NI) {
    int tid = blockIdx.x * 256 + (int)threadIdx.x;
    int per_row = NI >> 3;                 // threads per row (8 elems each)
    int n = tid / per_row;
    int ic = (tid - n * per_row) << 3;
    if (n >= N) return;
    const float4* src = (const float4*)(Wff + (size_t)n * NI + ic);
    float4 w0 = src[0], w1 = src[1];
    float wv[8] = {w0.x, w0.y, w0.z, w0.w, w1.x, w1.y, w1.z, w1.w};
    half8 hi, lo;
#pragma unroll
    for (int j = 0; j < 8; ++j) {
        float w = wv[j] * WSCALE;
        _Float16 h = (_Float16)w;
        hi[j] = h;
        lo[j] = (_Float16)(w - (float)h);
    }
    *(half8*)(Wt2 + (size_t)n * (2 * NI) + ic) = hi;
    *(half8*)(Wt2 + (size_t)n * (2 * NI) + NI + ic) = lo;
}

// ---- X prep: f16 copy of inputs (exact: values are 0/1) ----
__global__ __launch_bounds__(256) void k_xprep(const float* __restrict__ x,
                                               _Float16* __restrict__ X16,
                                               int total8) {
    int tid = blockIdx.x * 256 + (int)threadIdx.x;
    if (tid >= total8) return;
    const float4* src = (const float4*)(x + (size_t)tid * 8);
    float4 a = src[0], b = src[1];
    half8 o;
    o[0] = (_Float16)a.x; o[1] = (_Float16)a.y;
    o[2] = (_Float16)a.z; o[3] = (_Float16)a.w;
    o[4] = (_Float16)b.x; o[5] = (_Float16)b.y;
    o[6] = (_Float16)b.z; o[7] = (_Float16)b.w;
    *(half8*)(X16 + (size_t)tid * 8) = o;
}

// ---- merged chunk kernel ----
// blocks [0, nrec)       : recurrence over chunk c-1 (ff_src, tc_rec steps)
// blocks [nrec, nrec+nff): 128x128 GEMM tiles of ff chunk c.
//   nt = blk%32 -> with nrec%8==0, each XCD sees a fixed set of 4 n-panels
//   (2 MB of Wt2) -> B-operand L2-resident per XCD.
__global__ __launch_bounds__(256) void k_chunk(
    const _Float16* __restrict__ Wt2, const _Float16* __restrict__ X16,
    float* __restrict__ ff_dst, const float* __restrict__ ff_src,
    const float* __restrict__ vin, const float* __restrict__ cin,
    float* __restrict__ vout, float* __restrict__ cout,
    const int* __restrict__ ntype, const float* __restrict__ Evth_p,
    const float* __restrict__ Ivth_p,
    int T, int tc_ff, int t0_ff, int tc_rec, int N, int NI,
    float alpha, float beta, int nrec)
{
    __shared__ _Float16 smA[128 * 32];
    __shared__ _Float16 smB[128 * 32];
    int blk = blockIdx.x;
    if (blk < nrec) {
        // ---------- recurrence on previous chunk (cached loads) ----------
        int gid = blk * 256 + (int)threadIdx.x;
        int b = gid / N;
        int n = gid - b * N;
        float vth = (ntype[n] == 1) ? Evth_p[0] : Ivth_p[0];
        float v = vin[gid];
        float cur = cin[gid];
        const float* f = ff_src + (size_t)b * tc_rec * N + n;

#define STEP(x) \
        cur = __fadd_rn(__fmul_rn(alpha, cur), (x)); \
        v   = __fadd_rn(__fmul_rn(beta, v), cur);    \
        v   = (v >= vth) ? 0.0f : v;

        int t = 0;
        if (tc_rec >= 24) {
            float x[8], y[8], z[8];
#pragma unroll
            for (int k = 0; k < 8; ++k) x[k] = f[(size_t)k * N];
#pragma unroll
            for (int k = 0; k < 8; ++k) y[k] = f[(size_t)(8 + k) * N];
            for (t = 0; t + 24 <= tc_rec; t += 8) {
#pragma unroll
                for (int k = 0; k < 8; ++k) z[k] = f[(size_t)(t + 16 + k) * N];
#pragma unroll
                for (int k = 0; k < 8; ++k) { STEP(x[k]) }
#pragma unroll
                for (int k = 0; k < 8; ++k) { x[k] = y[k]; y[k] = z[k]; }
            }
#pragma unroll
            for (int k = 0; k < 8; ++k) { STEP(x[k]) }
#pragma unroll
            for (int k = 0; k < 8; ++k) { STEP(y[k]) }
            t += 16;
        }
        for (; t < tc_rec; ++t) {
            float x = f[(size_t)t * N];
            STEP(x)
        }
#undef STEP
        vout[gid] = v;
        cout[gid] = cur;
    } else {
        // ---------- ff GEMM tile: C[128 rows][128 cols] over K=2*NI ----------
        blk -= nrec;
        int Nt = N >> 7;                   // 32 n-tiles
        int mt = blk / Nt;
        int nt = blk - mt * Nt;
        int m0 = mt << 7, n0 = nt << 7;
        int wid = (int)threadIdx.x >> 6;
        int lane = (int)threadIdx.x & 63;
        int wr = wid >> 1, wc = wid & 1;
        int ln15 = lane & 15, kh = lane >> 4;

        // staging addresses: wave w, issue q covers LDS rows (w*2+q)*16..+16,
        // lane l -> row +(l>>2), 16B slot (l&3). A rows map chunk-row -> X row.
        const char* srcA[2]; const char* srcB[2];
        _Float16* dstA[2]; _Float16* dstB[2];
#pragma unroll
        for (int q = 0; q < 2; ++q) {
            int rr = wid * 32 + q * 16 + (lane >> 2);   // [0,128)
            int c16 = (lane & 3) << 3;                  // elem offset of slot
            int r = m0 + rr;                            // chunk row = b*tc + tl
            int b = r / tc_ff;
            int tl = r - b * tc_ff;
            srcA[q] = (const char*)(X16 + (size_t)(b * T + t0_ff + tl) * NI + c16);
            srcB[q] = (const char*)(Wt2 + (size_t)(n0 + rr) * (2 * NI) + c16);
            dstA[q] = smA + (size_t)(wid * 32 + q * 16) * 32;  // wave-uniform
            dstB[q] = smB + (size_t)(wid * 32 + q * 16) * 32;
        }

        floatx4 acc[4][4] = {};
        int kiters = NI >> 4;              // 2*NI/32
        int kmask = (NI >> 5) - 1;         // A source wraps over the two passes
        for (int kt = 0; kt < kiters; ++kt) {
            __syncthreads();               // previous compute done reading LDS
            int offA = (kt & kmask) << 6;  // bytes
            int offB = kt << 6;
            gload16(srcA[0] + offA, dstA[0]);
            gload16(srcA[1] + offA, dstA[1]);
            gload16(srcB[0] + offB, dstB[0]);
            gload16(srcB[1] + offB, dstB[1]);
            __syncthreads();               // compiler drains vmcnt(0) here
            half8 a[4], b[4];
#pragma unroll
            for (int i = 0; i < 4; ++i) {
                a[i] = *(const half8*)(smA + (size_t)(wr * 64 + i * 16 + ln15) * 32 + kh * 8);
                b[i] = *(const half8*)(smB + (size_t)(wc * 64 + i * 16 + ln15) * 32 + kh * 8);
            }
#pragma unroll
            for (int i = 0; i < 4; ++i)
#pragma unroll
                for (int j = 0; j < 4; ++j)
                    acc[i][j] = __builtin_amdgcn_mfma_f32_16x16x32_f16(
                        a[i], b[j], acc[i][j], 0, 0, 0);
        }
        // epilogue: C/D layout col=lane&15, row=(lane>>4)*4+e (guide-verified)
#pragma unroll
        for (int i = 0; i < 4; ++i) {
            int rbase = m0 + wr * 64 + i * 16 + kh * 4;
#pragma unroll
            for (int j = 0; j < 4; ++j) {
                int nn = n0 + wc * 64 + j * 16 + ln15;
                float* p = ff_dst + (size_t)rbase * N + nn;
#pragma unroll
                for (int e = 0; e < 4; ++e)
                    p[(size_t)e * N] = acc[i][j][e] * WSCALE_INV;
            }
        }
    }
}

extern "C" void kernel_launch(void* const* d_in, const int* in_sizes, int n_in,
                              void* d_out, int out_size, void* d_ws, size_t ws_size,
                              hipStream_t stream) {
    const float* initial_v = (const float*)d_in[0];
    const float* initial_I = (const float*)d_in[1];
    const float* inputs    = (const float*)d_in[2];
    // d_in[3] recurrent_weights: dead. d_in[5..6] E/I_weight: dead.
    const float* Wff       = (const float*)d_in[4];
    const float* Evth      = (const float*)d_in[7];
    const float* Ivth      = (const float*)d_in[8];
    const int*   ntype     = (const int*)d_in[9];

    const int N  = in_sizes[9];             // 4096
    const int B  = in_sizes[0] / N;         // 16
    const int NI = in_sizes[4] / N;         // 1024
    const int T  = in_sizes[2] / (B * NI);  // 1000

    char* ws = (char*)d_ws;
    _Float16* Wt2 = (_Float16*)ws;
    size_t wt_b  = (size_t)N * 2 * NI * sizeof(_Float16);
    _Float16* X16 = (_Float16*)(ws + wt_b);
    size_t x_b   = (size_t)B * T * NI * sizeof(_Float16);
    float* state = (float*)(ws + wt_b + x_b);             // [v | cur], 2*B*N
    size_t st_b  = (size_t)2 * B * N * sizeof(float);
    char*  ffbase = ws + wt_b + x_b + st_b;
    size_t fixed  = wt_b + x_b + st_b;

    // ping-pong chunk buffers; chunk length multiple of 8 (M tile = 128 rows)
    size_t avail = (ws_size > fixed) ? (ws_size - fixed) : 0;
    size_t per_t = (size_t)B * N * sizeof(float);
    int TC = (int)(avail / (2 * per_t));
    if (TC > 240) TC = 240;
    if (TC > T) TC = T;
    TC &= ~7;
    if (TC < 8) TC = 8;

    float* fbuf[2];
    fbuf[0] = (float*)ffbase;
    fbuf[1] = (float*)(ffbase + (size_t)TC * per_t);

    k_wprep<<<dim3((N * NI / 8 + 255) / 256), 256, 0, stream>>>(Wff, Wt2, N, NI);
    k_xprep<<<dim3((B * T * NI / 8 + 255) / 256), 256, 0, stream>>>(
        inputs, X16, B * T * NI / 8);

    const float alpha = (float)exp(-0.001 / 0.01);   // on current
    const float beta  = (float)exp(-0.001 / 0.005);  // on voltage

    float* st_v = state;
    float* st_c = state + (size_t)B * N;

    // chunk schedule: head 48 (exposed at ff-rate), full-TC middles, tail
    // split (rem-48, 48) so the final exposed rec is only 48 steps (rec-rate).
    static const int MAXCH = 1024;
    int t0s[MAXCH], tcs[MAXCH];
    int nch = 0;
    {
        int t0 = 0;
        int head = (TC >= 48) ? 48 : TC;
        if (head > T) head = T;
        t0s[nch] = 0; tcs[nch] = head; ++nch; t0 = head;
        while (t0 < T && nch < MAXCH) {
            int rem = T - t0;
            int tc;
            if (rem > TC + 48) {
                tc = TC;
            } else if (rem > 96) {
                tc = rem - 48;            // leaves exactly 48 for the tail
            } else {
                tc = rem;
            }
            t0s[nch] = t0; tcs[nch] = tc;
            t0 += tc; ++nch;
        }
    }

    // kernel k: ff(chunk k) [if k<nch] + rec(chunk k-1) [if k>=1]
    for (int k = 0; k <= nch; ++k) {
        int tc_ff  = (k < nch) ? tcs[k] : 0;
        int t0_ff  = (k < nch) ? t0s[k] : 0;
        int tc_rec = (k >= 1) ? tcs[k - 1] : 0;
        int nrec   = (k >= 1) ? (B * N) / 256 : 0;
        float* ffd = fbuf[k & 1];
        const float* ffs = fbuf[(k ^ 1) & 1];
        const float* vi = (k == 1) ? initial_v : st_v;
        const float* ci = (k == 1) ? initial_I : st_c;
        float* vo = (k == nch) ? (float*)d_out : st_v;
        float* co = (k == nch) ? ((float*)d_out + (size_t)B * N) : st_c;
        int nff = (tc_ff >> 3) * (N >> 7);   // (16*tc/128) * (N/128)
        int grid = nrec + nff;
        if (grid == 0) continue;
        k_chunk<<<dim3(grid), 256, 0, stream>>>(Wt2, X16, ffd, ffs,
                                                vi, ci, vo, co,
                                                ntype, Evth, Ivth,
                                                T, tc_ff, t0_ff, tc_rec, N, NI,
                                                alpha, beta, nrec);
    }
}

// Round 3
// 616.576 us; speedup vs baseline: 1.0446x; 1.0446x over previous
//
#include <hip/hip_runtime.h>
#include <cmath>
#include <cstdint>
#include <cstddef>

// LIF network. Facts exploited:
//  (1) s==0 forever -> recurrent term dead (recurrent_weights, E/I_weight unused).
//  (2) ff = X @ Wff^T is a GEMM; X is exactly 0/1 -> exact in f16. Weights
//      split f16 hi/lo with x1024 scaling (residual <= 2^-22 rel). K = 2048
//      (hi rows 0..1023, lo rows 1024..2047). Dense MFMA beats the sparse
//      L2-bound gather (27.5 TB/s, floor ~395 us).
//  (3) ff independent of recurrence -> per T-chunk kernel computes ff(chunk c)
//      via MFMA AND the serial recurrence over chunk c-1 (ping-pong buffers).
//  (4) X16 conversion for chunk c+1 is fused into kernel c as a third block
//      segment (GEMM is only ~19% HBM -> conversion rides for free).
//  GEMM: m97 recipe (128x128 tile, BK=32, 4 waves, [128][32] f16 LDS,
//      global_load_lds width 16, 2-barrier K-loop, 16x16x32 MFMA).
//  R1 post-mortem: [128][32] tile = 64B rows -> frag read was 8-way bank
//      conflict (7.86M/dispatch, MfmaUtil 22%). Fix: slot ^= (row>>1)&3
//      involution applied to BOTH the staging global source and the LDS read
//      (dest stays linear per global_load_lds rules) -> 2-way = free.
//  R2: fix const-qualifier compile error (separate writable X16 alias).
//
// ws layout: [ Wt2 (N x 2*NI) f16 | X16 (B*T x NI) f16 |
//              state 2*B*N f32 | ffA | ffB (TC*B*N f32 each) ]

typedef _Float16 half8 __attribute__((ext_vector_type(8)));
typedef float floatx4 __attribute__((ext_vector_type(4)));

#define WSCALE 1024.0f
#define WSCALE_INV (1.0f / 1024.0f)

__device__ __forceinline__ void gload16(const void* g, void* l) {
    __builtin_amdgcn_global_load_lds(
        (const __attribute__((address_space(1))) unsigned int*)g,
        (__attribute__((address_space(3))) unsigned int*)l, 16, 0, 0);
}

// ---- W prep: Wt2[n][k] f16, k<NI: hi(1024*Wff[n][k]); k>=NI: lo residual ----
__global__ __launch_bounds__(256) void k_wprep(const float* __restrict__ Wff,
                                               _Float16* __restrict__ Wt2,
                                               int N, int NI) {
    int tid = blockIdx.x * 256 + (int)threadIdx.x;
    int per_row = NI >> 3;                 // threads per row (8 elems each)
    int n = tid / per_row;
    int ic = (tid - n * per_row) << 3;
    if (n >= N) return;
    const float4* src = (const float4*)(Wff + (size_t)n * NI + ic);
    float4 w0 = src[0], w1 = src[1];
    float wv[8] = {w0.x, w0.y, w0.z, w0.w, w1.x, w1.y, w1.z, w1.w};
    half8 hi, lo;
#pragma unroll
    for (int j = 0; j < 8; ++j) {
        float w = wv[j] * WSCALE;
        _Float16 h = (_Float16)w;
        hi[j] = h;
        lo[j] = (_Float16)(w - (float)h);
    }
    *(half8*)(Wt2 + (size_t)n * (2 * NI) + ic) = hi;
    *(half8*)(Wt2 + (size_t)n * (2 * NI) + NI + ic) = lo;
}

// ---- X f32 -> f16 conversion for a T-range (exact: values are 0/1) ----
__device__ __forceinline__ void xconv_range(const float* __restrict__ x,
                                            _Float16* __restrict__ X16,
                                            int g0, int gstep, int xrows,
                                            int t0, int tc, int T, int NI) {
    int per_row = NI >> 3;
    int G = xrows * per_row;
    for (int g = g0; g < G; g += gstep) {
        int r = g / per_row;
        int gi = g - r * per_row;
        int b = r / tc;
        int tl = r - b * tc;
        size_t off = ((size_t)(b * T + t0 + tl) * NI) + ((size_t)gi << 3);
        const float4* src = (const float4*)(x + off);
        float4 a = src[0], c = src[1];
        half8 o;
        o[0] = (_Float16)a.x; o[1] = (_Float16)a.y;
        o[2] = (_Float16)a.z; o[3] = (_Float16)a.w;
        o[4] = (_Float16)c.x; o[5] = (_Float16)c.y;
        o[6] = (_Float16)c.z; o[7] = (_Float16)c.w;
        *(half8*)(X16 + off) = o;
    }
}

__global__ __launch_bounds__(256) void k_xpre(const float* __restrict__ x,
                                              _Float16* __restrict__ X16,
                                              int xrows, int t0, int tc,
                                              int T, int NI) {
    xconv_range(x, X16, blockIdx.x * 256 + (int)threadIdx.x,
                (int)gridDim.x * 256, xrows, t0, tc, T, NI);
}

// ---- merged chunk kernel ----
// blocks [0, nrec)            : recurrence over chunk c-1 (ff_src, tc_rec steps)
// blocks [nrec, nrec+nff)     : 128x128 GEMM tiles of ff chunk c.
// blocks [nrec+nff, end)      : X16 conversion for chunk c+1 (grid-stride).
//   nt = ffblk%32 -> with nrec%8==0, each XCD sees a fixed set of 4 n-panels
//   (2 MB of Wt2) -> B-operand L2-resident per XCD.
__global__ __launch_bounds__(256) void k_chunk(
    const _Float16* __restrict__ Wt2, const _Float16* __restrict__ X16,
    _Float16* __restrict__ x16w, const float* __restrict__ xin,
    float* __restrict__ ff_dst, const float* __restrict__ ff_src,
    const float* __restrict__ vin, const float* __restrict__ cin,
    float* __restrict__ vout, float* __restrict__ cout,
    const int* __restrict__ ntype, const float* __restrict__ Evth_p,
    const float* __restrict__ Ivth_p,
    int T, int tc_ff, int t0_ff, int tc_rec, int N, int NI,
    float alpha, float beta, int nrec, int nff,
    int xrows, int t0_x, int tc_x)
{
    __shared__ _Float16 smA[128 * 32];
    __shared__ _Float16 smB[128 * 32];
    int blk = blockIdx.x;
    if (blk < nrec) {
        // ---------- recurrence on previous chunk (cached loads) ----------
        int gid = blk * 256 + (int)threadIdx.x;
        int b = gid / N;
        int n = gid - b * N;
        float vth = (ntype[n] == 1) ? Evth_p[0] : Ivth_p[0];
        float v = vin[gid];
        float cur = cin[gid];
        const float* f = ff_src + (size_t)b * tc_rec * N + n;

#define STEP(x) \
        cur = __fadd_rn(__fmul_rn(alpha, cur), (x)); \
        v   = __fadd_rn(__fmul_rn(beta, v), cur);    \
        v   = (v >= vth) ? 0.0f : v;

        int t = 0;
        if (tc_rec >= 24) {
            float x[8], y[8], z[8];
#pragma unroll
            for (int k = 0; k < 8; ++k) x[k] = f[(size_t)k * N];
#pragma unroll
            for (int k = 0; k < 8; ++k) y[k] = f[(size_t)(8 + k) * N];
            for (t = 0; t + 24 <= tc_rec; t += 8) {
#pragma unroll
                for (int k = 0; k < 8; ++k) z[k] = f[(size_t)(t + 16 + k) * N];
#pragma unroll
                for (int k = 0; k < 8; ++k) { STEP(x[k]) }
#pragma unroll
                for (int k = 0; k < 8; ++k) { x[k] = y[k]; y[k] = z[k]; }
            }
#pragma unroll
            for (int k = 0; k < 8; ++k) { STEP(x[k]) }
#pragma unroll
            for (int k = 0; k < 8; ++k) { STEP(y[k]) }
            t += 16;
        }
        for (; t < tc_rec; ++t) {
            float x = f[(size_t)t * N];
            STEP(x)
        }
#undef STEP
        vout[gid] = v;
        cout[gid] = cur;
    } else if (blk < nrec + nff) {
        // ---------- ff GEMM tile: C[128 rows][128 cols] over K=2*NI ----------
        blk -= nrec;
        int Nt = N >> 7;                   // 32 n-tiles
        int mt = blk / Nt;
        int nt = blk - mt * Nt;
        int m0 = mt << 7, n0 = nt << 7;
        int wid = (int)threadIdx.x >> 6;
        int lane = (int)threadIdx.x & 63;
        int wr = wid >> 1, wc = wid & 1;
        int ln15 = lane & 15, kh = lane >> 4;

        // staging: wave w, issue q covers LDS rows (w*2+q)*16..+16, lane l ->
        // row +(l>>2), slot (l&3). Source slot pre-swizzled by the involution
        // slot ^= (row>>1)&3 (= (l>>3)&3 here); LDS dest stays linear.
        const char* srcA[2]; const char* srcB[2];
        _Float16* dstA[2]; _Float16* dstB[2];
#pragma unroll
        for (int q = 0; q < 2; ++q) {
            int rr = wid * 32 + q * 16 + (lane >> 2);   // [0,128)
            int slot = (lane & 3) ^ ((lane >> 3) & 3);  // ^= (rr>>1)&3
            int c16 = slot << 3;                        // f16 elem offset
            int r = m0 + rr;                            // chunk row = b*tc + tl
            int b = r / tc_ff;
            int tl = r - b * tc_ff;
            srcA[q] = (const char*)(X16 + (size_t)(b * T + t0_ff + tl) * NI + c16);
            srcB[q] = (const char*)(Wt2 + (size_t)(n0 + rr) * (2 * NI) + c16);
            dstA[q] = smA + (size_t)(wid * 32 + q * 16) * 32;  // wave-uniform
            dstB[q] = smB + (size_t)(wid * 32 + q * 16) * 32;
        }

        // fragment read slot swizzle: same involution, row bits from ln15
        int sa = (kh << 3) ^ (((ln15 >> 1) & 3) << 3);  // f16 elems

        floatx4 acc[4][4] = {};
        int kiters = NI >> 4;              // 2*NI/32
        int kmask = (NI >> 5) - 1;         // A source wraps over the two passes
        for (int kt = 0; kt < kiters; ++kt) {
            __syncthreads();               // previous compute done reading LDS
            int offA = (kt & kmask) << 6;  // bytes
            int offB = kt << 6;
            gload16(srcA[0] + offA, dstA[0]);
            gload16(srcA[1] + offA, dstA[1]);
            gload16(srcB[0] + offB, dstB[0]);
            gload16(srcB[1] + offB, dstB[1]);
            __syncthreads();               // compiler drains vmcnt(0) here
            half8 a[4], b[4];
#pragma unroll
            for (int i = 0; i < 4; ++i) {
                a[i] = *(const half8*)(smA + (size_t)(wr * 64 + i * 16 + ln15) * 32 + sa);
                b[i] = *(const half8*)(smB + (size_t)(wc * 64 + i * 16 + ln15) * 32 + sa);
            }
#pragma unroll
            for (int i = 0; i < 4; ++i)
#pragma unroll
                for (int j = 0; j < 4; ++j)
                    acc[i][j] = __builtin_amdgcn_mfma_f32_16x16x32_f16(
                        a[i], b[j], acc[i][j], 0, 0, 0);
        }
        // epilogue: C/D layout col=lane&15, row=(lane>>4)*4+e (guide-verified)
#pragma unroll
        for (int i = 0; i < 4; ++i) {
            int rbase = m0 + wr * 64 + i * 16 + kh * 4;
#pragma unroll
            for (int j = 0; j < 4; ++j) {
                int nn = n0 + wc * 64 + j * 16 + ln15;
                float* p = ff_dst + (size_t)rbase * N + nn;
#pragma unroll
                for (int e = 0; e < 4; ++e)
                    p[(size_t)e * N] = acc[i][j][e] * WSCALE_INV;
            }
        }
    } else {
        // ---------- X16 conversion for next chunk (rides under GEMM) -------
        int xb = blk - nrec - nff;
        int nxb = (int)gridDim.x - nrec - nff;
        xconv_range(xin, x16w, xb * 256 + (int)threadIdx.x, nxb * 256,
                    xrows, t0_x, tc_x, T, NI);
    }
}

extern "C" void kernel_launch(void* const* d_in, const int* in_sizes, int n_in,
                              void* d_out, int out_size, void* d_ws, size_t ws_size,
                              hipStream_t stream) {
    const float* initial_v = (const float*)d_in[0];
    const float* initial_I = (const float*)d_in[1];
    const float* inputs    = (const float*)d_in[2];
    // d_in[3] recurrent_weights: dead. d_in[5..6] E/I_weight: dead.
    const float* Wff       = (const float*)d_in[4];
    const float* Evth      = (const float*)d_in[7];
    const float* Ivth      = (const float*)d_in[8];
    const int*   ntype     = (const int*)d_in[9];

    const int N  = in_sizes[9];             // 4096
    const int B  = in_sizes[0] / N;         // 16
    const int NI = in_sizes[4] / N;         // 1024
    const int T  = in_sizes[2] / (B * NI);  // 1000

    char* ws = (char*)d_ws;
    _Float16* Wt2 = (_Float16*)ws;
    size_t wt_b  = (size_t)N * 2 * NI * sizeof(_Float16);
    _Float16* X16 = (_Float16*)(ws + wt_b);
    size_t x_b   = (size_t)B * T * NI * sizeof(_Float16);
    float* state = (float*)(ws + wt_b + x_b);             // [v | cur], 2*B*N
    size_t st_b  = (size_t)2 * B * N * sizeof(float);
    char*  ffbase = ws + wt_b + x_b + st_b;
    size_t fixed  = wt_b + x_b + st_b;

    // ping-pong chunk buffers; chunk length multiple of 8 (M tile = 128 rows)
    size_t avail = (ws_size > fixed) ? (ws_size - fixed) : 0;
    size_t per_t = (size_t)B * N * sizeof(float);
    int TC = (int)(avail / (2 * per_t));
    if (TC > 240) TC = 240;
    if (TC > T) TC = T;
    TC &= ~7;
    if (TC < 8) TC = 8;

    float* fbuf[2];
    fbuf[0] = (float*)ffbase;
    fbuf[1] = (float*)(ffbase + (size_t)TC * per_t);

    const float alpha = (float)exp(-0.001 / 0.01);   // on current
    const float beta  = (float)exp(-0.001 / 0.005);  // on voltage

    float* st_v = state;
    float* st_c = state + (size_t)B * N;

    // chunk schedule: head 48 (exposed at ff-rate), full-TC middles, tail
    // split (rem-48, 48) so the final exposed rec is only 48 steps (rec-rate).
    static const int MAXCH = 1024;
    int t0s[MAXCH], tcs[MAXCH];
    int nch = 0;
    {
        int t0 = 0;
        int head = (TC >= 48) ? 48 : TC;
        if (head > T) head = T;
        t0s[nch] = 0; tcs[nch] = head; ++nch; t0 = head;
        while (t0 < T && nch < MAXCH) {
            int rem = T - t0;
            int tc;
            if (rem > TC + 48) {
                tc = TC;
            } else if (rem > 96) {
                tc = rem - 48;            // leaves exactly 48 for the tail
            } else {
                tc = rem;
            }
            t0s[nch] = t0; tcs[nch] = tc;
            t0 += tc; ++nch;
        }
    }

    k_wprep<<<dim3((N * NI / 8 + 255) / 256), 256, 0, stream>>>(Wff, Wt2, N, NI);
    // convert only chunk 0's X slice up front; the rest rides inside k_chunk
    k_xpre<<<dim3(384), 256, 0, stream>>>(inputs, X16, B * tcs[0], 0, tcs[0], T, NI);

    // kernel k: ff(chunk k) [if k<nch] + rec(chunk k-1) [if k>=1]
    //         + xconv(chunk k+1) [if k+1<nch]
    for (int k = 0; k <= nch; ++k) {
        int tc_ff  = (k < nch) ? tcs[k] : 0;
        int t0_ff  = (k < nch) ? t0s[k] : 0;
        int tc_rec = (k >= 1) ? tcs[k - 1] : 0;
        int nrec   = (k >= 1) ? (B * N) / 256 : 0;
        int tc_x   = (k + 1 < nch) ? tcs[k + 1] : 0;
        int t0_x   = (k + 1 < nch) ? t0s[k + 1] : 0;
        int nxb    = (tc_x > 0) ? 256 : 0;
        float* ffd = fbuf[k & 1];
        const float* ffs = fbuf[(k ^ 1) & 1];
        const float* vi = (k == 1) ? initial_v : st_v;
        const float* ci = (k == 1) ? initial_I : st_c;
        float* vo = (k == nch) ? (float*)d_out : st_v;
        float* co = (k == nch) ? ((float*)d_out + (size_t)B * N) : st_c;
        int nff = (tc_ff >> 3) * (N >> 7);   // (16*tc/128) * (N/128)
        int grid = nrec + nff + nxb;
        if (grid == 0) continue;
        k_chunk<<<dim3(grid), 256, 0, stream>>>(Wt2, X16, X16, inputs, ffd, ffs,
                                                vi, ci, vo, co,
                                                ntype, Evth, Ivth,
                                                T, tc_ff, t0_ff, tc_rec, N, NI,
                                                alpha, beta, nrec, nff,
                                                B * tc_x, t0_x, tc_x);
    }
}

// Round 4
// 547.449 us; speedup vs baseline: 1.1765x; 1.1263x over previous
//
#include <hip/hip_runtime.h>
#include <cmath>
#include <cstdint>
#include <cstddef>

// LIF network. Facts exploited:
//  (1) s==0 forever -> recurrent term dead (recurrent_weights, E/I_weight unused).
//  (2) ff = X @ Wff^T is a GEMM; X is exactly 0/1 -> exact in f16. Weights
//      split f16 hi/lo with x1024 scaling (residual <= 2^-22 rel). K = 2048
//      (hi cols 0..1023, lo cols 1024..2047 share the same X cols via mask).
//  (3) ff independent of recurrence -> per T-chunk kernel computes ff(chunk c)
//      via MFMA AND the serial recurrence over chunk c-1 (ping-pong buffers).
//  (4) X16 conversion for chunk c+1 fused as a third block segment.
//  R3 post-mortem: swizzle killed bank conflicts (7.9M->0) but time flat ->
//      2-barrier structure is stage+drain+barrier-bound (~550 TF = m233's
//      2-phase ceiling). This version: T3+T4+T5 8-wave 256x256 BK=64 schedule,
//      counted vmcnt (never 0 mid-loop), raw s_barrier (no __syncthreads
//      vmcnt(0) drain), setprio around MFMA clusters.
//
//  vmcnt LEDGER (per wave; every thread issues 2 loads per stage-unit):
//    tile kt staged during kt-1's phases in order A0,B0,A1,B1 (slot kt&1).
//    gate G0 (before ph0 of kt): outstanding <= {A0,B0,A1,B1}(kt) = 8
//        -> vmcnt(4) waits oldest 4 = A0,B0(kt)   [needed by ph0/ph1]
//    ph0 issues A0(kt+1), ph1 issues B0(kt+1) into slot (kt+1)&1.
//    gate G1 (before ph2): outstanding <= {A1,B1}(kt)+{A0,B0}(kt+1) = 8
//        -> vmcnt(4) waits A1,B1(kt)              [needed by ph2/ph3]
//    ph2 issues A1(kt+1), ph3 issues B1(kt+1). Last tile: no staging, G1
//    becomes vmcnt(0) (epilogue drain). Slot-write vs slot-read hazards are
//    all separated by a memory-clobber asm wait + s_barrier (checked).
//
// ws layout: [ Wt2 (N x 2*NI) f16 | X16 (B*T x NI) f16 |
//              state 2*B*N f32 | ffA | ffB (TC*B*N f32 each) ]

typedef _Float16 half8 __attribute__((ext_vector_type(8)));
typedef float floatx4 __attribute__((ext_vector_type(4)));

#define WSCALE 1024.0f
#define WSCALE_INV (1.0f / 1024.0f)

#define VMW4 asm volatile("s_waitcnt vmcnt(4)" ::: "memory")
#define VMW0 asm volatile("s_waitcnt vmcnt(0)" ::: "memory")
#define BAR  __builtin_amdgcn_s_barrier()

__device__ __forceinline__ void gload16(const void* g, void* l) {
    __builtin_amdgcn_global_load_lds(
        (const __attribute__((address_space(1))) unsigned int*)g,
        (__attribute__((address_space(3))) unsigned int*)l, 16, 0, 0);
}

// ---- W prep: Wt2[n][k] f16, k<NI: hi(1024*Wff[n][k]); k>=NI: lo residual ----
__global__ __launch_bounds__(256) void k_wprep(const float* __restrict__ Wff,
                                               _Float16* __restrict__ Wt2,
                                               int N, int NI) {
    int tid = blockIdx.x * 256 + (int)threadIdx.x;
    int per_row = NI >> 3;
    int n = tid / per_row;
    int ic = (tid - n * per_row) << 3;
    if (n >= N) return;
    const float4* src = (const float4*)(Wff + (size_t)n * NI + ic);
    float4 w0 = src[0], w1 = src[1];
    float wv[8] = {w0.x, w0.y, w0.z, w0.w, w1.x, w1.y, w1.z, w1.w};
    half8 hi, lo;
#pragma unroll
    for (int j = 0; j < 8; ++j) {
        float w = wv[j] * WSCALE;
        _Float16 h = (_Float16)w;
        hi[j] = h;
        lo[j] = (_Float16)(w - (float)h);
    }
    *(half8*)(Wt2 + (size_t)n * (2 * NI) + ic) = hi;
    *(half8*)(Wt2 + (size_t)n * (2 * NI) + NI + ic) = lo;
}

// ---- X f32 -> f16 conversion for a T-range (exact: values are 0/1) ----
__device__ __forceinline__ void xconv_range(const float* __restrict__ x,
                                            _Float16* __restrict__ X16,
                                            int g0, int gstep, int xrows,
                                            int t0, int tc, int T, int NI) {
    int per_row = NI >> 3;
    int G = xrows * per_row;
    for (int g = g0; g < G; g += gstep) {
        int r = g / per_row;
        int gi = g - r * per_row;
        int b = r / tc;
        int tl = r - b * tc;
        size_t off = ((size_t)(b * T + t0 + tl) * NI) + ((size_t)gi << 3);
        const float4* src = (const float4*)(x + off);
        float4 a = src[0], c = src[1];
        half8 o;
        o[0] = (_Float16)a.x; o[1] = (_Float16)a.y;
        o[2] = (_Float16)a.z; o[3] = (_Float16)a.w;
        o[4] = (_Float16)c.x; o[5] = (_Float16)c.y;
        o[6] = (_Float16)c.z; o[7] = (_Float16)c.w;
        *(half8*)(X16 + off) = o;
    }
}

__global__ __launch_bounds__(256) void k_xpre(const float* __restrict__ x,
                                              _Float16* __restrict__ X16,
                                              int xrows, int t0, int tc,
                                              int T, int NI) {
    xconv_range(x, X16, blockIdx.x * 256 + (int)threadIdx.x,
                (int)gridDim.x * 256, xrows, t0, tc, T, NI);
}

// ---- merged chunk kernel (512 threads) ----
// blocks [0, nff)              : 256x256 GEMM tiles of ff chunk c (8-phase).
// blocks [nff, nff+nrec)       : recurrence over chunk c-1 (tc_rec steps).
// blocks [nff+nrec, end)       : X16 conversion for chunk c+1 (grid-stride).
//  GEMM first so nt = blk % (N/256): XCD x owns nt in {x, x+8} -> its two
//  1 MB B-panels stay L2-resident for the whole chunk.
__global__ __launch_bounds__(512, 2) void k_chunk(
    const _Float16* __restrict__ Wt2, const _Float16* __restrict__ X16,
    _Float16* __restrict__ x16w, const float* __restrict__ xin,
    float* __restrict__ ff_dst, const float* __restrict__ ff_src,
    const float* __restrict__ vin, const float* __restrict__ cin,
    float* __restrict__ vout, float* __restrict__ cout,
    const int* __restrict__ ntype, const float* __restrict__ Evth_p,
    const float* __restrict__ Ivth_p,
    int T, int tc_ff, int t0_ff, int tc_rec, int N, int NI,
    float alpha, float beta, int nff, int nrec, int mv,
    int xrows, int t0_x, int tc_x)
{
    // LDS: [dbuf slot][k-half][256 rows][32 k] f16 for A and B = 128 KiB
    __shared__ _Float16 smA[2][2][256 * 32];
    __shared__ _Float16 smB[2][2][256 * 32];
    int blk = blockIdx.x;
    int tid = (int)threadIdx.x;
    if (blk < nff) {
        // ---------- ff GEMM tile: C[256 rows][256 cols] over K=2*NI ----------
        int Ntiles = N >> 8;
        int mt = blk / Ntiles;
        int nt = blk - mt * Ntiles;
        int m0 = mt << 8, n0 = nt << 8;
        int wid = tid >> 6, lane = tid & 63;
        int wr = wid >> 2, wc = wid & 3;          // 2 x 4 wave grid
        int ln15 = lane & 15, kh = lane >> 4;

        // staging: unit = [256 rows][32 k] (16 KiB); per wave q in {0,1} covers
        // LDS rows (wid*2+q)*16..+16; lane -> row +(lane>>2), 16B slot (lane&3).
        // Source slot pre-swizzled by involution slot ^= (row>>1)&3 = (lane>>3)&3;
        // LDS dest stays linear (global_load_lds rule). Read side uses same
        // involution -> conflict-free (verified R3: conflicts 7.9M -> 0).
        int slot4 = (lane & 3) ^ ((lane >> 3) & 3);
        const char* srcA[2]; const char* srcB[2];
        int dB0 = (wid * 2) * 512;               // f16 index of dest block q=0
        int dB1 = dB0 + 512;
#pragma unroll
        for (int q = 0; q < 2; ++q) {
            int rl = (wid * 2 + q) * 16 + (lane >> 2);   // [0,256)
            int rA = m0 + rl;
            if (rA > mv - 1) rA = mv - 1;                // ragged-M clamp
            int b = rA / tc_ff;
            int tl = rA - b * tc_ff;
            srcA[q] = (const char*)(X16 + (size_t)(b * T + t0_ff + tl) * NI + slot4 * 8);
            srcB[q] = (const char*)(Wt2 + (size_t)(n0 + rl) * (2 * NI) + slot4 * 8);
        }
        int amask = NI - 1;                      // A col wraps over hi/lo passes

#define STAGE_A(S2, KS, KOFS) { \
        gload16(srcA[0] + (KOFS), &smA[S2][KS][dB0]); \
        gload16(srcA[1] + (KOFS), &smA[S2][KS][dB1]); }
#define STAGE_B(S2, KS, KOFS) { \
        gload16(srcB[0] + (KOFS), &smB[S2][KS][dB0]); \
        gload16(srcB[1] + (KOFS), &smB[S2][KS][dB1]); }

        // prologue: stage K-tile 0 into slot 0 (issue order A0,B0,A1,B1)
        STAGE_A(0, 0, 0);
        STAGE_B(0, 0, 0);
        STAGE_A(0, 1, 64);
        STAGE_B(0, 1, 64);

        // fragment read offsets (same involution, row bits from ln15)
        int sa  = ((kh ^ ((ln15 >> 1) & 3)) << 3);
        int aro = (wr * 128 + ln15) * 32 + sa;   // + mh*2048 + fi*512
        int bro = (wc * 64 + ln15) * 32 + sa;    // + fj*512

        floatx4 acc[8][4] = {};
        int NKT = (2 * NI) >> 6;                 // 32 K-tiles of 64

        for (int kt = 0; kt < NKT; ++kt) {
            int s = kt & 1, s2 = s ^ 1;
            bool pre = (kt + 1 < NKT);
            int j64 = (kt + 1) << 6;
            int kA0 = ((j64) & amask) * 2;       // byte offsets for next tile
            int kA1 = ((j64 + 32) & amask) * 2;
            int kB0 = j64 * 2;
            int kB1 = (j64 + 32) * 2;
            half8 a[4], b[4];
            // -------- phase 0: gate A0,B0(kt); k-half 0, m-half 0 --------
            VMW4; BAR;
#pragma unroll
            for (int f = 0; f < 4; ++f) b[f] = *(const half8*)(&smB[s][0][bro + f * 512]);
#pragma unroll
            for (int f = 0; f < 4; ++f) a[f] = *(const half8*)(&smA[s][0][aro + f * 512]);
            if (pre) STAGE_A(s2, 0, kA0);
            __builtin_amdgcn_s_setprio(1);
#pragma unroll
            for (int fi = 0; fi < 4; ++fi)
#pragma unroll
                for (int fj = 0; fj < 4; ++fj)
                    acc[fi][fj] = __builtin_amdgcn_mfma_f32_16x16x32_f16(a[fi], b[fj], acc[fi][fj], 0, 0, 0);
            __builtin_amdgcn_s_setprio(0);
            BAR;
            // -------- phase 1: k-half 0, m-half 1 (B frags reused) --------
#pragma unroll
            for (int f = 0; f < 4; ++f) a[f] = *(const half8*)(&smA[s][0][aro + 2048 + f * 512]);
            if (pre) STAGE_B(s2, 0, kB0);
            __builtin_amdgcn_s_setprio(1);
#pragma unroll
            for (int fi = 0; fi < 4; ++fi)
#pragma unroll
                for (int fj = 0; fj < 4; ++fj)
                    acc[4 + fi][fj] = __builtin_amdgcn_mfma_f32_16x16x32_f16(a[fi], b[fj], acc[4 + fi][fj], 0, 0, 0);
            __builtin_amdgcn_s_setprio(0);
            BAR;
            // -------- phase 2: gate A1,B1(kt); k-half 1, m-half 0 --------
            if (pre) { VMW4; } else { VMW0; }
            BAR;
#pragma unroll
            for (int f = 0; f < 4; ++f) b[f] = *(const half8*)(&smB[s][1][bro + f * 512]);
#pragma unroll
            for (int f = 0; f < 4; ++f) a[f] = *(const half8*)(&smA[s][1][aro + f * 512]);
            if (pre) STAGE_A(s2, 1, kA1);
            __builtin_amdgcn_s_setprio(1);
#pragma unroll
            for (int fi = 0; fi < 4; ++fi)
#pragma unroll
                for (int fj = 0; fj < 4; ++fj)
                    acc[fi][fj] = __builtin_amdgcn_mfma_f32_16x16x32_f16(a[fi], b[fj], acc[fi][fj], 0, 0, 0);
            __builtin_amdgcn_s_setprio(0);
            BAR;
            // -------- phase 3: k-half 1, m-half 1 --------
#pragma unroll
            for (int f = 0; f < 4; ++f) a[f] = *(const half8*)(&smA[s][1][aro + 2048 + f * 512]);
            if (pre) STAGE_B(s2, 1, kB1);
            __builtin_amdgcn_s_setprio(1);
#pragma unroll
            for (int fi = 0; fi < 4; ++fi)
#pragma unroll
                for (int fj = 0; fj < 4; ++fj)
                    acc[4 + fi][fj] = __builtin_amdgcn_mfma_f32_16x16x32_f16(a[fi], b[fj], acc[4 + fi][fj], 0, 0, 0);
            __builtin_amdgcn_s_setprio(0);
            BAR;
        }
#undef STAGE_A
#undef STAGE_B
        // epilogue: C/D layout col=lane&15, row=(lane>>4)*4+e (harness-verified)
#pragma unroll
        for (int ai = 0; ai < 8; ++ai) {
            int r0 = m0 + wr * 128 + (ai >> 2) * 64 + (ai & 3) * 16 + kh * 4;
#pragma unroll
            for (int fj = 0; fj < 4; ++fj) {
                int nn = n0 + wc * 64 + fj * 16 + ln15;
                float* p = ff_dst + (size_t)r0 * N + nn;
#pragma unroll
                for (int e = 0; e < 4; ++e)
                    if (r0 + e < mv) p[(size_t)e * N] = acc[ai][fj][e] * WSCALE_INV;
            }
        }
    } else if (blk < nff + nrec) {
        // ---------- recurrence on previous chunk (cached loads) ----------
        int gid = (blk - nff) * 512 + tid;
        int b = gid / N;
        int n = gid - b * N;
        float vth = (ntype[n] == 1) ? Evth_p[0] : Ivth_p[0];
        float v = vin[gid];
        float cur = cin[gid];
        const float* f = ff_src + (size_t)b * tc_rec * N + n;

#define STEP(x) \
        cur = __fadd_rn(__fmul_rn(alpha, cur), (x)); \
        v   = __fadd_rn(__fmul_rn(beta, v), cur);    \
        v   = (v >= vth) ? 0.0f : v;

        int t = 0;
        if (tc_rec >= 24) {
            float x[8], y[8], z[8];
#pragma unroll
            for (int k = 0; k < 8; ++k) x[k] = f[(size_t)k * N];
#pragma unroll
            for (int k = 0; k < 8; ++k) y[k] = f[(size_t)(8 + k) * N];
            for (t = 0; t + 24 <= tc_rec; t += 8) {
#pragma unroll
                for (int k = 0; k < 8; ++k) z[k] = f[(size_t)(t + 16 + k) * N];
#pragma unroll
                for (int k = 0; k < 8; ++k) { STEP(x[k]) }
#pragma unroll
                for (int k = 0; k < 8; ++k) { x[k] = y[k]; y[k] = z[k]; }
            }
#pragma unroll
            for (int k = 0; k < 8; ++k) { STEP(x[k]) }
#pragma unroll
            for (int k = 0; k < 8; ++k) { STEP(y[k]) }
            t += 16;
        }
        for (; t < tc_rec; ++t) {
            float x = f[(size_t)t * N];
            STEP(x)
        }
#undef STEP
        vout[gid] = v;
        cout[gid] = cur;
    } else {
        // ---------- X16 conversion for next chunk (rides under GEMM) -------
        int xb = blk - nff - nrec;
        int nxb = (int)gridDim.x - nff - nrec;
        xconv_range(xin, x16w, xb * 512 + tid, nxb * 512,
                    xrows, t0_x, tc_x, T, NI);
    }
}

extern "C" void kernel_launch(void* const* d_in, const int* in_sizes, int n_in,
                              void* d_out, int out_size, void* d_ws, size_t ws_size,
                              hipStream_t stream) {
    const float* initial_v = (const float*)d_in[0];
    const float* initial_I = (const float*)d_in[1];
    const float* inputs    = (const float*)d_in[2];
    // d_in[3] recurrent_weights: dead. d_in[5..6] E/I_weight: dead.
    const float* Wff       = (const float*)d_in[4];
    const float* Evth      = (const float*)d_in[7];
    const float* Ivth      = (const float*)d_in[8];
    const int*   ntype     = (const int*)d_in[9];

    const int N  = in_sizes[9];             // 4096
    const int B  = in_sizes[0] / N;         // 16
    const int NI = in_sizes[4] / N;         // 1024
    const int T  = in_sizes[2] / (B * NI);  // 1000

    char* ws = (char*)d_ws;
    _Float16* Wt2 = (_Float16*)ws;
    size_t wt_b  = (size_t)N * 2 * NI * sizeof(_Float16);
    _Float16* X16 = (_Float16*)(ws + wt_b);
    size_t x_b   = (size_t)B * T * NI * sizeof(_Float16);
    float* state = (float*)(ws + wt_b + x_b);             // [v | cur], 2*B*N
    size_t st_b  = (size_t)2 * B * N * sizeof(float);
    char*  ffbase = ws + wt_b + x_b + st_b;
    size_t fixed  = wt_b + x_b + st_b;

    // ping-pong chunk buffers
    size_t avail = (ws_size > fixed) ? (ws_size - fixed) : 0;
    size_t per_t = (size_t)B * N * sizeof(float);
    int TC = (int)(avail / (2 * per_t));
    if (TC > 240) TC = 240;
    if (TC > T) TC = T;
    TC &= ~7;
    if (TC < 8) TC = 8;

    float* fbuf[2];
    fbuf[0] = (float*)ffbase;
    fbuf[1] = (float*)(ffbase + (size_t)TC * per_t);

    const float alpha = (float)exp(-0.001 / 0.01);   // on current
    const float beta  = (float)exp(-0.001 / 0.005);  // on voltage

    float* st_v = state;
    float* st_c = state + (size_t)B * N;

    // chunk schedule: head 48 (exposed at ff-rate), full-TC middles, tail
    // split (rem-48, 48) so the final exposed rec is only 48 steps.
    static const int MAXCH = 1024;
    int t0s[MAXCH], tcs[MAXCH];
    int nch = 0;
    {
        int t0 = 0;
        int head = (TC >= 48) ? 48 : TC;
        if (head > T) head = T;
        t0s[nch] = 0; tcs[nch] = head; ++nch; t0 = head;
        while (t0 < T && nch < MAXCH) {
            int rem = T - t0;
            int tc;
            if (rem > TC + 48) {
                tc = TC;
            } else if (rem > 96) {
                tc = rem - 48;
            } else {
                tc = rem;
            }
            t0s[nch] = t0; tcs[nch] = tc;
            t0 += tc; ++nch;
        }
    }

    k_wprep<<<dim3((N * NI / 8 + 255) / 256), 256, 0, stream>>>(Wff, Wt2, N, NI);
    // convert only chunk 0's X slice up front; the rest rides inside k_chunk
    k_xpre<<<dim3(384), 256, 0, stream>>>(inputs, X16, B * tcs[0], 0, tcs[0], T, NI);

    // kernel k: ff(chunk k) [if k<nch] + rec(chunk k-1) [if k>=1]
    //         + xconv(chunk k+1) [if k+1<nch]
    for (int k = 0; k <= nch; ++k) {
        int tc_ff  = (k < nch) ? tcs[k] : 0;
        int t0_ff  = (k < nch) ? t0s[k] : 0;
        int tc_rec = (k >= 1) ? tcs[k - 1] : 0;
        int nrec   = (k >= 1) ? (B * N) / 512 : 0;
        int tc_x   = (k + 1 < nch) ? tcs[k + 1] : 0;
        int t0_x   = (k + 1 < nch) ? t0s[k + 1] : 0;
        int nxb    = (tc_x > 0) ? 64 : 0;
        float* ffd = fbuf[k & 1];
        const float* ffs = fbuf[(k ^ 1) & 1];
        const float* vi = (k == 1) ? initial_v : st_v;
        const float* ci = (k == 1) ? initial_I : st_c;
        float* vo = (k == nch) ? (float*)d_out : st_v;
        float* co = (k == nch) ? ((float*)d_out + (size_t)B * N) : st_c;
        int mv  = B * tc_ff;
        int nff = (tc_ff > 0) ? (((mv + 255) >> 8) * (N >> 8)) : 0;
        int grid = nff + nrec + nxb;
        if (grid == 0) continue;
        k_chunk<<<dim3(grid), 512, 0, stream>>>(Wt2, X16, X16, inputs, ffd, ffs,
                                                vi, ci, vo, co,
                                                ntype, Evth, Ivth,
                                                T, tc_ff, t0_ff, tc_rec, N, NI,
                                                alpha, beta, nff, nrec, mv,
                                                B * tc_x, t0_x, tc_x);
    }
}